// Round 5
// baseline (347.924 us; speedup 1.0000x reference)
//
#include <hip/hip_runtime.h>
#include <math.h>

#define BATCH 256
#define M 128        // txt rows
#define NIMG 127     // valid img cols
#define NP 128       // padded img cols
#define D 1024
#define BK 64        // k-tile
#define NT (D / BK)  // 16 k-tiles (full-K fallback)
#define KH 512       // K-half for the split kernel
#define NT2 (KH / BK) // 8 k-tiles per half
#define ITERS 50
#define LROW 72      // LDS row stride in bf16 elems (64 + 8 pad)

typedef __attribute__((ext_vector_type(8))) short bf16x8;
typedef __attribute__((ext_vector_type(4))) float floatx4;

// pack two floats to bf16x2 (RNE), bit-level
static __device__ __forceinline__ unsigned pack_bf16x2(float a, float b) {
    unsigned ua = __builtin_bit_cast(unsigned, a);
    unsigned ub = __builtin_bit_cast(unsigned, b);
    ua += 0x7fffu + ((ua >> 16) & 1u);
    ub += 0x7fffu + ((ub >> 16) & 1u);
    return (ua >> 16) | (ub & 0xffff0000u);
}

// DPP row_ror:n add (16-lane rotate) — VALU-pipe reduction, no DS ops
template<int CTRL>
static __device__ __forceinline__ float dpp_add(float v) {
    int s = __builtin_amdgcn_update_dpp(0, __builtin_bit_cast(int, v), CTRL, 0xf, 0xf, true);
    return v + __builtin_bit_cast(float, s);
}
// full 16-lane (DPP row) sum, result in all 16 lanes
static __device__ __forceinline__ float red16(float v) {
    v = dpp_add<0x121>(v);   // row_ror:1
    v = dpp_add<0x122>(v);   // row_ror:2
    v = dpp_add<0x124>(v);   // row_ror:4
    v = dpp_add<0x128>(v);   // row_ror:8
    return v;
}

// raw barrier: ds_write visibility via explicit lgkmcnt(0); no vmcnt drain,
// so prefetched global loads stay in flight across the barrier.
static __device__ __forceinline__ void barrier_lgkm() {
    asm volatile("s_waitcnt lgkmcnt(0)" ::: "memory");
    __builtin_amdgcn_s_barrier();
    __builtin_amdgcn_sched_barrier(0);
}

// ---------------- shared K1 helpers (128-row tile geometry) ----------------
static __device__ __forceinline__ void load_tile(const float* __restrict__ xb,
                                                 const float* __restrict__ yb,
                                                 int kk, int r0, int c16,
                                                 float4 (&vx)[4], float4 (&vy)[4]) {
#pragma unroll
    for (int it = 0; it < 4; ++it) {
        const int r = r0 + it * 32;
        vx[it] = *(const float4*)(xb + (size_t)r * D + kk + c16 * 4);
        float4 z = make_float4(0.f, 0.f, 0.f, 0.f);
        if (r < NIMG) z = *(const float4*)(yb + (size_t)r * D + kk + c16 * 4);
        vy[it] = z;
    }
}

static __device__ __forceinline__ void stage_tile(short* __restrict__ Xs, short* __restrict__ Ys,
                                                  int r0, int c16,
                                                  const float4 (&vx)[4], const float4 (&vy)[4],
                                                  float (&ssx)[4], float (&ssy)[4]) {
#pragma unroll
    for (int it = 0; it < 4; ++it) {
        const int r = r0 + it * 32;
        float4 v = vx[it];
        ssx[it] = fmaf(v.x, v.x, fmaf(v.y, v.y, fmaf(v.z, v.z, fmaf(v.w, v.w, ssx[it]))));
        uint2 p;
        p.x = pack_bf16x2(v.x, v.y);
        p.y = pack_bf16x2(v.z, v.w);
        *(uint2*)(&Xs[r * LROW + c16 * 4]) = p;
        v = vy[it];
        ssy[it] = fmaf(v.x, v.x, fmaf(v.y, v.y, fmaf(v.z, v.z, fmaf(v.w, v.w, ssy[it]))));
        p.x = pack_bf16x2(v.x, v.y);
        p.y = pack_bf16x2(v.z, v.w);
        *(uint2*)(&Ys[r * LROW + c16 * 4]) = p;
    }
}

static __device__ __forceinline__ void mfma_tile(const short* __restrict__ Xs,
                                                 const short* __restrict__ Ys,
                                                 int mbase, int nbase, int col, int quad,
                                                 floatx4 (&acc)[2][4]) {
#pragma unroll
    for (int ks = 0; ks < 2; ++ks) {
        const int koff = ks * 32 + quad * 8;
        bf16x8 af[2], bfr[4];
#pragma unroll
        for (int tr = 0; tr < 2; ++tr)
            af[tr] = *(const bf16x8*)(&Xs[(mbase + tr * 16 + col) * LROW + koff]);
#pragma unroll
        for (int tc = 0; tc < 4; ++tc)
            bfr[tc] = *(const bf16x8*)(&Ys[(nbase + tc * 16 + col) * LROW + koff]);
#pragma unroll
        for (int tr = 0; tr < 2; ++tr)
#pragma unroll
            for (int tc = 0; tc < 4; ++tc)
                acc[tr][tc] = __builtin_amdgcn_mfma_f32_16x16x32_bf16(
                    af[tr], bfr[tc], acc[tr][tc], 0, 0, 0);
    }
}

// ---------------- K1 (new): K-split GEMM -> raw C-partials + norm partials --
// grid = 512: block bid handles batch bid>>1, K-half bid&1. 2 blocks/CU
// (LDS 72KB x2 = 144KB <= 160KB) so one block's MFMA/barrier phases overlap
// the other's load phases (m114 mechanism; m102: 1->multi blocks/CU is the
// dominant lever at this shape). No input duplication: each byte read once.
// A is NOT formed here — ipot_fused reads both C-halves and applies
// norm/exp/mask in registers (A was register-resident there anyway).
__launch_bounds__(512, 2)
__global__ void gemm_c_kernel(const float* __restrict__ xg,
                              const float* __restrict__ yg,
                              float* __restrict__ Cp,     // [512][128][128] f32
                              float* __restrict__ NXp,    // [512][128] row sumsq partials (txt)
                              float* __restrict__ NYp)    // [512][128] row sumsq partials (img)
{
    __shared__ __align__(16) short Xs[2][M * LROW];
    __shared__ __align__(16) short Ys[2][M * LROW];

    const int bid = blockIdx.x;
    const int b   = bid >> 1;
    const int kh  = bid & 1;
    const int t   = threadIdx.x;
    const int lane = t & 63;
    const int w    = t >> 6;

    const float* xb = xg + (size_t)b * M * D + kh * KH;
    const float* yb = yg + ((size_t)b * 128 + 1) * D + kh * KH;

    const int r0  = t >> 4;
    const int c16 = t & 15;

    floatx4 acc[2][4];
#pragma unroll
    for (int a = 0; a < 2; ++a)
#pragma unroll
        for (int c = 0; c < 4; ++c) acc[a][c] = (floatx4)0.0f;

    float ssx[4] = {0.f, 0.f, 0.f, 0.f};
    float ssy[4] = {0.f, 0.f, 0.f, 0.f};

    const int mbase = (w & 3) * 32;
    const int nbase = (w >> 2) * 64;
    const int col   = lane & 15;
    const int quad  = lane >> 4;

    // 2-deep register prefetch + dbuf LDS, one raw barrier per k-tile
    float4 vxa[4], vya[4], vxb[4], vyb[4];
    load_tile(xb, yb, 0,  r0, c16, vxa, vya);
    load_tile(xb, yb, BK, r0, c16, vxb, vyb);

#pragma unroll 1
    for (int ii = 0; ii < NT2; ii += 2) {
        stage_tile(Xs[0], Ys[0], r0, c16, vxa, vya, ssx, ssy);
        if (ii + 2 < NT2) load_tile(xb, yb, (ii + 2) * BK, r0, c16, vxa, vya);
        barrier_lgkm();
        mfma_tile(Xs[0], Ys[0], mbase, nbase, col, quad, acc);
        stage_tile(Xs[1], Ys[1], r0, c16, vxb, vyb, ssx, ssy);
        if (ii + 3 < NT2) load_tile(xb, yb, (ii + 3) * BK, r0, c16, vxb, vyb);
        barrier_lgkm();
        mfma_tile(Xs[1], Ys[1], mbase, nbase, col, quad, acc);
    }

    // row sumsq partials for this K-half (DPP across the 16 c16 lanes)
#pragma unroll
    for (int it = 0; it < 4; ++it) {
        ssx[it] = red16(ssx[it]);
        ssy[it] = red16(ssy[it]);
    }
    if (c16 == 0) {
#pragma unroll
        for (int it = 0; it < 4; ++it) {
            const int r = r0 + it * 32;
            NXp[(size_t)bid * M + r] = ssx[it];
            NYp[(size_t)bid * M + r] = ssy[it];
        }
    }

    // epilogue: raw C-partial store (no norm/exp/mask here)
    float* Cb = Cp + (size_t)bid * M * NP;
#pragma unroll
    for (int tr = 0; tr < 2; ++tr)
#pragma unroll
        for (int tc = 0; tc < 4; ++tc) {
            const int n = nbase + tc * 16 + col;
#pragma unroll
            for (int reg = 0; reg < 4; ++reg) {
                const int m = mbase + tr * 16 + quad * 4 + reg;
                Cb[m * NP + n] = acc[tr][tc][reg];
            }
        }
}

// ---------------- K2 (new): fused A-formation + 50 IPOT iterations ----------
__launch_bounds__(512, 1)
__global__ void ipot_fused_kernel(const float* __restrict__ Cp,
                                  const float* __restrict__ NXp,
                                  const float* __restrict__ NYp,
                                  const int* __restrict__ xnum,
                                  const int* __restrict__ ynum,
                                  float* __restrict__ out)
{
    __shared__ __align__(16) float partCS[8 * 128];
    __shared__ __align__(16) float sdelta[NP];
    __shared__ __align__(16) float sxmask[M];
    __shared__ __align__(16) float symask[NP];
    __shared__ __align__(16) float sinvx[M];
    __shared__ __align__(16) float sinvy[NP];
    __shared__ float sxl_s, syl_s;
    __shared__ unsigned scnt[16];
    __shared__ float swsum[8];

    const int b    = blockIdx.x;
    const int t    = threadIdx.x;
    const int lane = t & 63;
    const int w    = t >> 6;
    const int tj   = t & 15;
    const int i0   = (t >> 4) * 4;
    const int j0   = tj * 8;

    bool tpad = true, ipad = true;
    if (t < M)  { tpad = (xnum[b * M + t] == 0); sxmask[t] = tpad ? 1e4f : 0.0f; }
    if (t < NP) { ipad = !(t < NIMG && ynum[b * 128 + t + 1] != 0); symask[t] = ipad ? 1e4f : 0.0f; }
    // inverse row norms from the two K-half sumsq partials
    if (t < M) {
        const float q = NXp[(size_t)(2 * b) * M + t] + NXp[(size_t)(2 * b + 1) * M + t];
        sinvx[t] = 1.0f / fmaxf(sqrtf(q), 1e-5f);
    }
    if (t < NP) {
        const float q = NYp[(size_t)(2 * b) * M + t] + NYp[(size_t)(2 * b + 1) * M + t];
        sinvy[t] = 1.0f / fmaxf(sqrtf(q), 1e-5f);
    }
    unsigned long long bx = __ballot(t < M  && !tpad);
    unsigned long long by = __ballot(t < NP && !ipad);
    if (lane == 0) { scnt[w] = (unsigned)__popcll(bx); scnt[8 + w] = (unsigned)__popcll(by); }
    __syncthreads();
    if (t == 0) {
        float xl = 0.f, yl = 0.f;
        for (int k = 0; k < 8; ++k) { xl += scnt[k]; yl += scnt[8 + k]; }
        sxl_s = xl; syl_s = yl;
    }
    __syncthreads();
    const float xl = sxl_s, yl = syl_s;

    // hoist masks + norms into registers (constant across iterations)
    float xm[4], ym[8], ivx[4], ivy[8];
    *(float4*)xm       = *(const float4*)(&sxmask[i0]);
    *(float4*)ym       = *(const float4*)(&symask[j0]);
    *(float4*)(ym + 4) = *(const float4*)(&symask[j0 + 4]);
    *(float4*)ivx       = *(const float4*)(&sinvx[i0]);
    *(float4*)ivy       = *(const float4*)(&sinvy[j0]);
    *(float4*)(ivy + 4) = *(const float4*)(&sinvy[j0 + 4]);

    // sigma carried in registers
    float sn[4];
#pragma unroll
    for (int r = 0; r < 4; ++r)
        sn[r] = (xm[r] > 0.0f) ? 0.0f : __builtin_amdgcn_rcpf(xl);

    // A = exp(2*cos - 2) masked, formed in registers from the C-partials
    const float* C0 = Cp + (size_t)(2 * b) * M * NP;
    const float* C1 = Cp + (size_t)(2 * b + 1) * M * NP;
    float Af[4][8], Q[4][8];
#pragma unroll
    for (int r = 0; r < 4; ++r) {
        float4 a0 = *(const float4*)(C0 + (size_t)(i0 + r) * NP + j0);
        float4 a1 = *(const float4*)(C0 + (size_t)(i0 + r) * NP + j0 + 4);
        float4 b0 = *(const float4*)(C1 + (size_t)(i0 + r) * NP + j0);
        float4 b1 = *(const float4*)(C1 + (size_t)(i0 + r) * NP + j0 + 4);
        float c[8] = {a0.x + b0.x, a0.y + b0.y, a0.z + b0.z, a0.w + b0.w,
                      a1.x + b1.x, a1.y + b1.y, a1.z + b1.z, a1.w + b1.w};
#pragma unroll
        for (int j = 0; j < 8; ++j) {
            const bool pad = (xm[r] > 0.0f) || (ym[j] > 0.0f);
            const float p  = c[j] * ivx[r] * ivy[j];
            Af[r][j] = pad ? 0.0f : expf(2.0f * p - 2.0f);
            Q[r][j]  = Af[r][j];
        }
    }

    float lp = 0.0f;
    for (int itn = 0; itn < ITERS; ++itn) {
        // ---- colsum[j] = sum_i sigma[i] Q[i][j] ----
        float cp[8] = {0.f,0.f,0.f,0.f,0.f,0.f,0.f,0.f};
#pragma unroll
        for (int r = 0; r < 4; ++r)
#pragma unroll
            for (int j = 0; j < 8; ++j)
                cp[j] = fmaf(sn[r], Q[r][j], cp[j]);
#pragma unroll
        for (int j = 0; j < 8; ++j) {
            cp[j] += __shfl_xor(cp[j], 16);
            cp[j] += __shfl_xor(cp[j], 32);
        }
        if (lane < 16) {
            float4 c0 = make_float4(cp[0], cp[1], cp[2], cp[3]);
            float4 c1 = make_float4(cp[4], cp[5], cp[6], cp[7]);
            *(float4*)(&partCS[w * 128 + j0])     = c0;
            *(float4*)(&partCS[w * 128 + j0 + 4]) = c1;
        }
        __syncthreads();
        if (t < NP) {
            float s = 0.f;
#pragma unroll
            for (int w8 = 0; w8 < 8; ++w8) s += partCS[w8 * 128 + t];
            sdelta[t] = __builtin_amdgcn_rcpf(yl * s + symask[t]);
        }
        __syncthreads();
        // ---- rowsum[i] = sum_j delta[j] Q[i][j] ----
        float dl[8];
        *(float4*)dl       = *(const float4*)(&sdelta[j0]);
        *(float4*)(dl + 4) = *(const float4*)(&sdelta[j0 + 4]);
        float rp[4] = {0.f, 0.f, 0.f, 0.f};
#pragma unroll
        for (int r = 0; r < 4; ++r)
#pragma unroll
            for (int j = 0; j < 8; ++j)
                rp[r] = fmaf(dl[j], Q[r][j], rp[r]);
#pragma unroll
        for (int r = 0; r < 4; ++r) rp[r] = red16(rp[r]);
#pragma unroll
        for (int r = 0; r < 4; ++r) rp[r] = __shfl(rp[r], lane & 48);
#pragma unroll
        for (int r = 0; r < 4; ++r)
            sn[r] = __builtin_amdgcn_rcpf(xl * rp[r] + xm[r]);

        if (itn < ITERS - 1) {
#pragma unroll
            for (int r = 0; r < 4; ++r) {
                const float f = sn[r];
#pragma unroll
                for (int j = 0; j < 8; ++j)
                    Q[r][j] *= Af[r][j] * dl[j] * f;
            }
        } else {
#pragma unroll
            for (int r = 0; r < 4; ++r)
#pragma unroll
                for (int j = 0; j < 8; ++j) {
                    const float a = Af[r][j];
                    if (a > 0.0f)
                        lp = fmaf(-0.5f * logf(a) * dl[j] * sn[r], Q[r][j], lp);
                }
        }
    }

#pragma unroll
    for (int off = 32; off > 0; off >>= 1) lp += __shfl_down(lp, off);
    if (lane == 0) swsum[w] = lp;
    __syncthreads();
    if (t == 0) {
        float tot = 0.f;
        for (int k = 0; k < 8; ++k) tot += swsum[k];
        atomicAdd(out, 0.01f * tot);
    }
}

// =================== fallback path (R4 kernels, unchanged) ===================
__launch_bounds__(512, 1)
__global__ void gemm_a_kernel(const float* __restrict__ xg,
                              const float* __restrict__ yg,
                              const int* __restrict__ xnum,
                              const int* __restrict__ ynum,
                              float* __restrict__ Aout)
{
    __shared__ __align__(16) short Xs[2][M * LROW];
    __shared__ __align__(16) short Ys[2][M * LROW];
    __shared__ __align__(16) float sinvx[M];
    __shared__ __align__(16) float sinvy[NP];
    __shared__ __align__(16) float sxmask[M];
    __shared__ __align__(16) float symask[NP];

    const int b    = blockIdx.x;
    const int t    = threadIdx.x;
    const int lane = t & 63;
    const int w    = t >> 6;

    const float* xb = xg + (size_t)b * M * D;
    const float* yb = yg + ((size_t)b * 128 + 1) * D;

    if (t < M)  sxmask[t] = (xnum[b * M + t] == 0) ? 1.0f : 0.0f;
    if (t < NP) symask[t] = (t < NIMG && ynum[b * 128 + t + 1] != 0) ? 0.0f : 1.0f;

    const int r0  = t >> 4;
    const int c16 = t & 15;

    floatx4 acc[2][4];
#pragma unroll
    for (int a = 0; a < 2; ++a)
#pragma unroll
        for (int c = 0; c < 4; ++c) acc[a][c] = (floatx4)0.0f;

    float ssx[4] = {0.f, 0.f, 0.f, 0.f};
    float ssy[4] = {0.f, 0.f, 0.f, 0.f};

    const int mbase = (w & 3) * 32;
    const int nbase = (w >> 2) * 64;
    const int col   = lane & 15;
    const int quad  = lane >> 4;

    float4 vxa[4], vya[4], vxb[4], vyb[4];
    load_tile(xb, yb, 0,  r0, c16, vxa, vya);
    load_tile(xb, yb, BK, r0, c16, vxb, vyb);

#pragma unroll 1
    for (int ii = 0; ii < NT; ii += 2) {
        stage_tile(Xs[0], Ys[0], r0, c16, vxa, vya, ssx, ssy);
        if (ii + 2 < NT) load_tile(xb, yb, (ii + 2) * BK, r0, c16, vxa, vya);
        barrier_lgkm();
        mfma_tile(Xs[0], Ys[0], mbase, nbase, col, quad, acc);
        stage_tile(Xs[1], Ys[1], r0, c16, vxb, vyb, ssx, ssy);
        if (ii + 3 < NT) load_tile(xb, yb, (ii + 3) * BK, r0, c16, vxb, vyb);
        barrier_lgkm();
        mfma_tile(Xs[1], Ys[1], mbase, nbase, col, quad, acc);
    }

#pragma unroll
    for (int it = 0; it < 4; ++it) {
        ssx[it] = red16(ssx[it]);
        ssy[it] = red16(ssy[it]);
    }
    if (c16 == 0) {
#pragma unroll
        for (int it = 0; it < 4; ++it) {
            const int r = r0 + it * 32;
            sinvx[r] = 1.0f / fmaxf(sqrtf(ssx[it]), 1e-5f);
            sinvy[r] = 1.0f / fmaxf(sqrtf(ssy[it]), 1e-5f);
        }
    }
    barrier_lgkm();

    float* Ab = Aout + (size_t)b * M * NP;
#pragma unroll
    for (int tr = 0; tr < 2; ++tr)
#pragma unroll
        for (int tc = 0; tc < 4; ++tc) {
            const int n = nbase + tc * 16 + col;
            const float ivy_n = sinvy[n];
            const float ymf   = symask[n];
#pragma unroll
            for (int reg = 0; reg < 4; ++reg) {
                const int m = mbase + tr * 16 + quad * 4 + reg;
                const float p = acc[tr][tc][reg] * sinvx[m] * ivy_n;
                const float a = (sxmask[m] + ymf > 0.0f) ? 0.0f : expf(2.0f * p - 2.0f);
                Ab[m * NP + n] = a;
            }
        }
}

__launch_bounds__(512, 1)
__global__ void ipot_kernel(const float* __restrict__ Ain,
                            const int* __restrict__ xnum,
                            const int* __restrict__ ynum,
                            float* __restrict__ out)
{
    __shared__ __align__(16) float partCS[8 * 128];
    __shared__ __align__(16) float sdelta[NP];
    __shared__ __align__(16) float sxmask[M];
    __shared__ __align__(16) float symask[NP];
    __shared__ float sxl_s, syl_s;
    __shared__ unsigned scnt[16];
    __shared__ float swsum[8];

    const int b    = blockIdx.x;
    const int t    = threadIdx.x;
    const int lane = t & 63;
    const int w    = t >> 6;
    const int tj   = t & 15;
    const int i0   = (t >> 4) * 4;
    const int j0   = tj * 8;

    bool tpad = true, ipad = true;
    if (t < M)  { tpad = (xnum[b * M + t] == 0); sxmask[t] = tpad ? 1e4f : 0.0f; }
    if (t < NP) { ipad = !(t < NIMG && ynum[b * 128 + t + 1] != 0); symask[t] = ipad ? 1e4f : 0.0f; }
    unsigned long long bx = __ballot(t < M  && !tpad);
    unsigned long long by = __ballot(t < NP && !ipad);
    if (lane == 0) { scnt[w] = (unsigned)__popcll(bx); scnt[8 + w] = (unsigned)__popcll(by); }
    __syncthreads();
    if (t == 0) {
        float xl = 0.f, yl = 0.f;
        for (int k = 0; k < 8; ++k) { xl += scnt[k]; yl += scnt[8 + k]; }
        sxl_s = xl; syl_s = yl;
    }
    __syncthreads();
    const float xl = sxl_s, yl = syl_s;

    float xm[4], ym[8];
    *(float4*)xm       = *(const float4*)(&sxmask[i0]);
    *(float4*)ym       = *(const float4*)(&symask[j0]);
    *(float4*)(ym + 4) = *(const float4*)(&symask[j0 + 4]);

    float sn[4];
#pragma unroll
    for (int r = 0; r < 4; ++r)
        sn[r] = (xm[r] > 0.0f) ? 0.0f : __builtin_amdgcn_rcpf(xl);

    const float* Ab = Ain + (size_t)b * M * NP;
    float Af[4][8], Q[4][8];
#pragma unroll
    for (int r = 0; r < 4; ++r) {
        float4 a0 = *(const float4*)(Ab + (size_t)(i0 + r) * NP + j0);
        float4 a1 = *(const float4*)(Ab + (size_t)(i0 + r) * NP + j0 + 4);
        Af[r][0] = a0.x; Af[r][1] = a0.y; Af[r][2] = a0.z; Af[r][3] = a0.w;
        Af[r][4] = a1.x; Af[r][5] = a1.y; Af[r][6] = a1.z; Af[r][7] = a1.w;
#pragma unroll
        for (int j = 0; j < 8; ++j) Q[r][j] = Af[r][j];
    }

    float lp = 0.0f;
    for (int itn = 0; itn < ITERS; ++itn) {
        float cp[8] = {0.f,0.f,0.f,0.f,0.f,0.f,0.f,0.f};
#pragma unroll
        for (int r = 0; r < 4; ++r)
#pragma unroll
            for (int j = 0; j < 8; ++j)
                cp[j] = fmaf(sn[r], Q[r][j], cp[j]);
#pragma unroll
        for (int j = 0; j < 8; ++j) {
            cp[j] += __shfl_xor(cp[j], 16);
            cp[j] += __shfl_xor(cp[j], 32);
        }
        if (lane < 16) {
            float4 c0 = make_float4(cp[0], cp[1], cp[2], cp[3]);
            float4 c1 = make_float4(cp[4], cp[5], cp[6], cp[7]);
            *(float4*)(&partCS[w * 128 + j0])     = c0;
            *(float4*)(&partCS[w * 128 + j0 + 4]) = c1;
        }
        __syncthreads();
        if (t < NP) {
            float s = 0.f;
#pragma unroll
            for (int w8 = 0; w8 < 8; ++w8) s += partCS[w8 * 128 + t];
            sdelta[t] = __builtin_amdgcn_rcpf(yl * s + symask[t]);
        }
        __syncthreads();
        float dl[8];
        *(float4*)dl       = *(const float4*)(&sdelta[j0]);
        *(float4*)(dl + 4) = *(const float4*)(&sdelta[j0 + 4]);
        float rp[4] = {0.f, 0.f, 0.f, 0.f};
#pragma unroll
        for (int r = 0; r < 4; ++r)
#pragma unroll
            for (int j = 0; j < 8; ++j)
                rp[r] = fmaf(dl[j], Q[r][j], rp[r]);
#pragma unroll
        for (int r = 0; r < 4; ++r) rp[r] = red16(rp[r]);
#pragma unroll
        for (int r = 0; r < 4; ++r) rp[r] = __shfl(rp[r], lane & 48);
#pragma unroll
        for (int r = 0; r < 4; ++r)
            sn[r] = __builtin_amdgcn_rcpf(xl * rp[r] + xm[r]);

        if (itn < ITERS - 1) {
#pragma unroll
            for (int r = 0; r < 4; ++r) {
                const float f = sn[r];
#pragma unroll
                for (int j = 0; j < 8; ++j)
                    Q[r][j] *= Af[r][j] * dl[j] * f;
            }
        } else {
#pragma unroll
            for (int r = 0; r < 4; ++r)
#pragma unroll
                for (int j = 0; j < 8; ++j) {
                    const float a = Af[r][j];
                    if (a > 0.0f)
                        lp = fmaf(-0.5f * logf(a) * dl[j] * sn[r], Q[r][j], lp);
                }
        }
    }

#pragma unroll
    for (int off = 32; off > 0; off >>= 1) lp += __shfl_down(lp, off);
    if (lane == 0) swsum[w] = lp;
    __syncthreads();
    if (t == 0) {
        float tot = 0.f;
        for (int k = 0; k < 8; ++k) tot += swsum[k];
        atomicAdd(out, 0.01f * tot);
    }
}

extern "C" void kernel_launch(void* const* d_in, const int* in_sizes, int n_in,
                              void* d_out, int out_size, void* d_ws, size_t ws_size,
                              hipStream_t stream) {
    const float* x  = (const float*)d_in[0];
    const float* y  = (const float*)d_in[1];
    const int*   xn = (const int*)d_in[2];
    const int*   yn = (const int*)d_in[3];
    float* out = (float*)d_out;

    (void)hipMemsetAsync(out, 0, (size_t)out_size * sizeof(float), stream);

    // workspace layout for the K-split path:
    //   Cp  : 2*BATCH * M * NP floats = 33.55 MB
    //   NXp : 2*BATCH * M floats      = 0.26 MB
    //   NYp : 2*BATCH * M floats      = 0.26 MB
    const size_t cpFloats = (size_t)2 * BATCH * M * NP;
    const size_t nFloats  = (size_t)2 * BATCH * M;
    const size_t needBytes = (cpFloats + 2 * nFloats) * sizeof(float);

    if (ws_size >= needBytes) {
        float* Cp  = (float*)d_ws;
        float* NXp = Cp + cpFloats;
        float* NYp = NXp + nFloats;
        gemm_c_kernel<<<dim3(2 * BATCH), dim3(512), 0, stream>>>(x, y, Cp, NXp, NYp);
        ipot_fused_kernel<<<dim3(BATCH), dim3(512), 0, stream>>>(Cp, NXp, NYp, xn, yn, out);
    } else {
        // fallback: R4 measured path (A materialized in ws)
        float* A = (float*)d_ws;   // 16.8 MB
        gemm_a_kernel<<<dim3(BATCH), dim3(512), 0, stream>>>(x, y, xn, yn, A);
        ipot_kernel<<<dim3(BATCH), dim3(512), 0, stream>>>(A, xn, yn, out);
    }
}

// Round 6
// 343.570 us; speedup vs baseline: 1.0127x; 1.0127x over previous
//
#include <hip/hip_runtime.h>
#include <math.h>

#define BATCH 256
#define M 128        // txt rows
#define NIMG 127     // valid img cols
#define NP 128       // padded img cols
#define D 1024
#define BK 64        // k-tile
#define NT (D / BK)  // 16 k-tiles
#define ITERS 50
#define LROW 72      // LDS row stride in bf16 elems (64 + 8 pad)
#define ASTRIDE 132  // A-LDS row stride in floats (128 + 4: breaks write bank conflicts)

typedef __attribute__((ext_vector_type(8))) short bf16x8;
typedef __attribute__((ext_vector_type(4))) float floatx4;

// pack two floats to bf16x2 (RNE), bit-level
static __device__ __forceinline__ unsigned pack_bf16x2(float a, float b) {
    unsigned ua = __builtin_bit_cast(unsigned, a);
    unsigned ub = __builtin_bit_cast(unsigned, b);
    ua += 0x7fffu + ((ua >> 16) & 1u);
    ub += 0x7fffu + ((ub >> 16) & 1u);
    return (ua >> 16) | (ub & 0xffff0000u);
}

// DPP row_ror:n add (16-lane rotate) — VALU-pipe reduction, no DS ops
template<int CTRL>
static __device__ __forceinline__ float dpp_add(float v) {
    int s = __builtin_amdgcn_update_dpp(0, __builtin_bit_cast(int, v), CTRL, 0xf, 0xf, true);
    return v + __builtin_bit_cast(float, s);
}
// full 16-lane (DPP row) sum, result in all 16 lanes
static __device__ __forceinline__ float red16(float v) {
    v = dpp_add<0x121>(v);   // row_ror:1
    v = dpp_add<0x122>(v);   // row_ror:2
    v = dpp_add<0x124>(v);   // row_ror:4
    v = dpp_add<0x128>(v);   // row_ror:8
    return v;
}

// raw barrier: ds_write visibility via explicit lgkmcnt(0); no vmcnt drain,
// so prefetched global loads stay in flight across the barrier.
static __device__ __forceinline__ void barrier_lgkm() {
    asm volatile("s_waitcnt lgkmcnt(0)" ::: "memory");
    __builtin_amdgcn_s_barrier();
    __builtin_amdgcn_sched_barrier(0);
}

// ---------------- GEMM-phase helpers (full 128 x 128 tile) ----------------
static __device__ __forceinline__ void load_tile(const float* __restrict__ xb,
                                                 const float* __restrict__ yb,
                                                 int kk, int r0, int c16,
                                                 float4 (&vx)[4], float4 (&vy)[4]) {
#pragma unroll
    for (int it = 0; it < 4; ++it) {
        const int r = r0 + it * 32;
        vx[it] = *(const float4*)(xb + (size_t)r * D + kk + c16 * 4);
        float4 z = make_float4(0.f, 0.f, 0.f, 0.f);
        if (r < NIMG) z = *(const float4*)(yb + (size_t)r * D + kk + c16 * 4);
        vy[it] = z;
    }
}

static __device__ __forceinline__ void stage_tile(short* __restrict__ Xs, short* __restrict__ Ys,
                                                  int r0, int c16,
                                                  const float4 (&vx)[4], const float4 (&vy)[4],
                                                  float (&ssx)[4], float (&ssy)[4]) {
#pragma unroll
    for (int it = 0; it < 4; ++it) {
        const int r = r0 + it * 32;
        float4 v = vx[it];
        ssx[it] = fmaf(v.x, v.x, fmaf(v.y, v.y, fmaf(v.z, v.z, fmaf(v.w, v.w, ssx[it]))));
        uint2 p;
        p.x = pack_bf16x2(v.x, v.y);
        p.y = pack_bf16x2(v.z, v.w);
        *(uint2*)(&Xs[r * LROW + c16 * 4]) = p;
        v = vy[it];
        ssy[it] = fmaf(v.x, v.x, fmaf(v.y, v.y, fmaf(v.z, v.z, fmaf(v.w, v.w, ssy[it]))));
        p.x = pack_bf16x2(v.x, v.y);
        p.y = pack_bf16x2(v.z, v.w);
        *(uint2*)(&Ys[r * LROW + c16 * 4]) = p;
    }
}

static __device__ __forceinline__ void mfma_tile(const short* __restrict__ Xs,
                                                 const short* __restrict__ Ys,
                                                 int mbase, int nbase, int col, int quad,
                                                 floatx4 (&acc)[2][4]) {
#pragma unroll
    for (int ks = 0; ks < 2; ++ks) {
        const int koff = ks * 32 + quad * 8;
        bf16x8 af[2], bfr[4];
#pragma unroll
        for (int tr = 0; tr < 2; ++tr)
            af[tr] = *(const bf16x8*)(&Xs[(mbase + tr * 16 + col) * LROW + koff]);
#pragma unroll
        for (int tc = 0; tc < 4; ++tc)
            bfr[tc] = *(const bf16x8*)(&Ys[(nbase + tc * 16 + col) * LROW + koff]);
#pragma unroll
        for (int tr = 0; tr < 2; ++tr)
#pragma unroll
            for (int tc = 0; tc < 4; ++tc)
                acc[tr][tc] = __builtin_amdgcn_mfma_f32_16x16x32_bf16(
                    af[tr], bfr[tc], acc[tr][tc], 0, 0, 0);
    }
}

// ============ FUSED: cosine-GEMM -> A (in LDS) -> 50 IPOT iters -> loss =====
// One block per batch. A never touches HBM: the gemm Xs/Ys LDS pool (73.7KB)
// is dead after the k-loop and is reused as A[128][ASTRIDE] f32 (67.6KB).
// Removes: A write+read (16.8+16.8MB), one kernel launch, and the device-wide
// drain between dependent kernels (slowest gemm block no longer gates all
// ipot blocks — each CU pipelines its own gemm->ipot).
__launch_bounds__(512, 1)
__global__ void fused_kernel(const float* __restrict__ xg,
                             const float* __restrict__ yg,
                             const int* __restrict__ xnum,
                             const int* __restrict__ ynum,
                             float* __restrict__ out)
{
    // 73728-byte pool: gemm phase = Xs[2]/Ys[2] bf16 tiles; ipot phase = A f32
    __shared__ __align__(16) unsigned char smem[2 * M * LROW * 2 * sizeof(short)];
    __shared__ __align__(16) float partCS[8 * 128];
    __shared__ __align__(16) float sdelta[NP];
    __shared__ __align__(16) float sxmask[M];
    __shared__ __align__(16) float symask[NP];
    __shared__ __align__(16) float sinvx[M];
    __shared__ __align__(16) float sinvy[NP];
    __shared__ float sxl_s, syl_s;
    __shared__ unsigned scnt[16];
    __shared__ float swsum[8];

    short (*Xs)[M * LROW] = reinterpret_cast<short (*)[M * LROW]>(smem);
    short (*Ys)[M * LROW] = reinterpret_cast<short (*)[M * LROW]>(smem + 2 * M * LROW * sizeof(short));
    float* Alds = reinterpret_cast<float*>(smem);   // 128*132*4 = 67584 <= 73728

    const int b    = blockIdx.x;
    const int t    = threadIdx.x;
    const int lane = t & 63;
    const int w    = t >> 6;
    const int tj   = t & 15;
    const int i0   = (t >> 4) * 4;   // ipot row base
    const int j0   = tj * 8;         // ipot col base

    // ---- masks + valid-lengths (once, before any global prefetch) ----
    bool tpad = true, ipad = true;
    if (t < M)  { tpad = (xnum[b * M + t] == 0); sxmask[t] = tpad ? 1e4f : 0.0f; }
    if (t < NP) { ipad = !(t < NIMG && ynum[b * 128 + t + 1] != 0); symask[t] = ipad ? 1e4f : 0.0f; }
    unsigned long long bx = __ballot(t < M  && !tpad);
    unsigned long long by = __ballot(t < NP && !ipad);
    if (lane == 0) { scnt[w] = (unsigned)__popcll(bx); scnt[8 + w] = (unsigned)__popcll(by); }
    __syncthreads();
    if (t == 0) {
        float xl = 0.f, yl = 0.f;
        for (int k = 0; k < 8; ++k) { xl += scnt[k]; yl += scnt[8 + k]; }
        sxl_s = xl; syl_s = yl;
    }

    // ---- GEMM phase (R4 structure: dbuf LDS, 2-deep reg prefetch, raw barriers)
    const float* xb = xg + (size_t)b * M * D;
    const float* yb = yg + ((size_t)b * 128 + 1) * D;

    const int r0  = t >> 4;
    const int c16 = t & 15;

    floatx4 acc[2][4];
#pragma unroll
    for (int a = 0; a < 2; ++a)
#pragma unroll
        for (int c = 0; c < 4; ++c) acc[a][c] = (floatx4)0.0f;

    float ssx[4] = {0.f, 0.f, 0.f, 0.f};
    float ssy[4] = {0.f, 0.f, 0.f, 0.f};

    const int mbase = (w & 3) * 32;
    const int nbase = (w >> 2) * 64;
    const int col   = lane & 15;
    const int quad  = lane >> 4;

    float4 vxa[4], vya[4], vxb[4], vyb[4];
    load_tile(xb, yb, 0,  r0, c16, vxa, vya);
    load_tile(xb, yb, BK, r0, c16, vxb, vyb);
    __syncthreads();   // covers sxl_s/scnt writes above (one-time; nothing to drain yet)

#pragma unroll 1
    for (int ii = 0; ii < NT; ii += 2) {
        stage_tile(Xs[0], Ys[0], r0, c16, vxa, vya, ssx, ssy);
        if (ii + 2 < NT) load_tile(xb, yb, (ii + 2) * BK, r0, c16, vxa, vya);
        barrier_lgkm();
        mfma_tile(Xs[0], Ys[0], mbase, nbase, col, quad, acc);
        stage_tile(Xs[1], Ys[1], r0, c16, vxb, vyb, ssx, ssy);
        if (ii + 3 < NT) load_tile(xb, yb, (ii + 3) * BK, r0, c16, vxb, vyb);
        barrier_lgkm();
        mfma_tile(Xs[1], Ys[1], mbase, nbase, col, quad, acc);
    }

    // ---- row-norm reduction (DPP across the 16 c16 lanes per row) ----
#pragma unroll
    for (int it = 0; it < 4; ++it) {
        ssx[it] = red16(ssx[it]);
        ssy[it] = red16(ssy[it]);
    }
    if (c16 == 0) {
#pragma unroll
        for (int it = 0; it < 4; ++it) {
            const int r = r0 + it * 32;
            sinvx[r] = 1.0f / fmaxf(sqrtf(ssx[it]), 1e-5f);
            sinvy[r] = 1.0f / fmaxf(sqrtf(ssy[it]), 1e-5f);
        }
    }
    // after this barrier every thread is past its k-loop LDS reads (each
    // thread's ds_reads were consumed into acc before it arrived) -> the
    // Xs/Ys pool may be safely overwritten with A
    barrier_lgkm();

    // ---- epilogue: A = exp(2*cos - 2) masked, into LDS (gemm acc layout) ----
#pragma unroll
    for (int tr = 0; tr < 2; ++tr)
#pragma unroll
        for (int tc = 0; tc < 4; ++tc) {
            const int n = nbase + tc * 16 + col;
            const float ivy_n = sinvy[n];
            const float ymf   = symask[n];
#pragma unroll
            for (int reg = 0; reg < 4; ++reg) {
                const int m = mbase + tr * 16 + quad * 4 + reg;
                const float p = acc[tr][tc][reg] * sinvx[m] * ivy_n;
                const float a = (sxmask[m] + ymf > 0.0f) ? 0.0f : expf(2.0f * p - 2.0f);
                Alds[m * ASTRIDE + n] = a;
            }
        }
    barrier_lgkm();

    // ---- IPOT phase (R4/R1 structure, best measured) ----
    const float xl = sxl_s, yl = syl_s;

    float xm[4], ym[8];
    *(float4*)xm       = *(const float4*)(&sxmask[i0]);
    *(float4*)ym       = *(const float4*)(&symask[j0]);
    *(float4*)(ym + 4) = *(const float4*)(&symask[j0 + 4]);

    float sn[4];
#pragma unroll
    for (int r = 0; r < 4; ++r)
        sn[r] = (xm[r] > 0.0f) ? 0.0f : __builtin_amdgcn_rcpf(xl);

    float Af[4][8], Q[4][8];
#pragma unroll
    for (int r = 0; r < 4; ++r) {
        float4 a0 = *(const float4*)(&Alds[(i0 + r) * ASTRIDE + j0]);
        float4 a1 = *(const float4*)(&Alds[(i0 + r) * ASTRIDE + j0 + 4]);
        Af[r][0] = a0.x; Af[r][1] = a0.y; Af[r][2] = a0.z; Af[r][3] = a0.w;
        Af[r][4] = a1.x; Af[r][5] = a1.y; Af[r][6] = a1.z; Af[r][7] = a1.w;
#pragma unroll
        for (int j = 0; j < 8; ++j) Q[r][j] = Af[r][j];
    }
    __syncthreads();   // Alds reads done before partCS/sdelta traffic begins

    float lp = 0.0f;
    for (int itn = 0; itn < ITERS; ++itn) {
        // ---- colsum[j] = sum_i sigma[i] Q[i][j] ----
        float cp[8] = {0.f,0.f,0.f,0.f,0.f,0.f,0.f,0.f};
#pragma unroll
        for (int r = 0; r < 4; ++r)
#pragma unroll
            for (int j = 0; j < 8; ++j)
                cp[j] = fmaf(sn[r], Q[r][j], cp[j]);
#pragma unroll
        for (int j = 0; j < 8; ++j) {
            cp[j] += __shfl_xor(cp[j], 16);
            cp[j] += __shfl_xor(cp[j], 32);
        }
        if (lane < 16) {
            float4 c0 = make_float4(cp[0], cp[1], cp[2], cp[3]);
            float4 c1 = make_float4(cp[4], cp[5], cp[6], cp[7]);
            *(float4*)(&partCS[w * 128 + j0])     = c0;
            *(float4*)(&partCS[w * 128 + j0 + 4]) = c1;
        }
        __syncthreads();
        if (t < NP) {
            float s = 0.f;
#pragma unroll
            for (int w8 = 0; w8 < 8; ++w8) s += partCS[w8 * 128 + t];
            sdelta[t] = __builtin_amdgcn_rcpf(yl * s + symask[t]);
        }
        __syncthreads();
        // ---- rowsum[i] = sum_j delta[j] Q[i][j] ----
        float dl[8];
        *(float4*)dl       = *(const float4*)(&sdelta[j0]);
        *(float4*)(dl + 4) = *(const float4*)(&sdelta[j0 + 4]);
        float rp[4] = {0.f, 0.f, 0.f, 0.f};
#pragma unroll
        for (int r = 0; r < 4; ++r)
#pragma unroll
            for (int j = 0; j < 8; ++j)
                rp[r] = fmaf(dl[j], Q[r][j], rp[r]);
        // 16-lane DPP reduce, then broadcast the group leader's value so all
        // 16 lanes use bit-identical sigma
#pragma unroll
        for (int r = 0; r < 4; ++r) rp[r] = red16(rp[r]);
#pragma unroll
        for (int r = 0; r < 4; ++r) rp[r] = __shfl(rp[r], lane & 48);
#pragma unroll
        for (int r = 0; r < 4; ++r)
            sn[r] = __builtin_amdgcn_rcpf(xl * rp[r] + xm[r]);

        if (itn < ITERS - 1) {
#pragma unroll
            for (int r = 0; r < 4; ++r) {
                const float f = sn[r];
#pragma unroll
                for (int j = 0; j < 8; ++j)
                    Q[r][j] *= Af[r][j] * dl[j] * f;
            }
        } else {
#pragma unroll
            for (int r = 0; r < 4; ++r)
#pragma unroll
                for (int j = 0; j < 8; ++j) {
                    const float a = Af[r][j];
                    if (a > 0.0f)
                        lp = fmaf(-0.5f * logf(a) * dl[j] * sn[r], Q[r][j], lp);
                }
        }
    }

#pragma unroll
    for (int off = 32; off > 0; off >>= 1) lp += __shfl_down(lp, off);
    if (lane == 0) swsum[w] = lp;
    __syncthreads();
    if (t == 0) {
        float tot = 0.f;
        for (int k = 0; k < 8; ++k) tot += swsum[k];
        atomicAdd(out, 0.01f * tot);
    }
}

extern "C" void kernel_launch(void* const* d_in, const int* in_sizes, int n_in,
                              void* d_out, int out_size, void* d_ws, size_t ws_size,
                              hipStream_t stream) {
    const float* x  = (const float*)d_in[0];
    const float* y  = (const float*)d_in[1];
    const int*   xn = (const int*)d_in[2];
    const int*   yn = (const int*)d_in[3];
    float* out = (float*)d_out;
    (void)d_ws; (void)ws_size;

    (void)hipMemsetAsync(out, 0, (size_t)out_size * sizeof(float), stream);
    fused_kernel<<<dim3(BATCH), dim3(512), 0, stream>>>(x, y, xn, yn, out);
}